// Round 12
// baseline (1219.955 us; speedup 1.0000x reference)
//
#include <hip/hip_runtime.h>
#include <math.h>

namespace {

constexpr int   STEPS = 100;
constexpr int   BATCH = 2048;
constexpr float DT    = 0.05f;
constexpr float DAMP  = 0.01f;
constexpr float EPSV  = 1e-8f;
constexpr int   LDW   = 130; // R2-proven stride (0 conflicts measured)

typedef float f32x2 __attribute__((ext_vector_type(2)));

// Dual FP32 FMA (one VOP3P issue). acc.lo += s.lo*w.SEL; acc.hi += s.hi*w.SEL.
// Weight-half replication via op_sel (no splat movs). Each half is an exact
// IEEE FMA -> bitwise-identical to the scalar fmaf pair it replaces.
__device__ __forceinline__ void pk_wlo(f32x2& acc, f32x2 s, f32x2 w) {
  asm("v_pk_fma_f32 %0, %1, %2, %0 op_sel:[0,0,0] op_sel_hi:[1,0,1]"
      : "+v"(acc) : "v"(s), "v"(w));
}
__device__ __forceinline__ void pk_whi(f32x2& acc, f32x2 s, f32x2 w) {
  asm("v_pk_fma_f32 %0, %1, %2, %0 op_sel:[0,1,0] op_sel_hi:[1,1,1]"
      : "+v"(acc) : "v"(s), "v"(w));
}

// DPP-assisted cross-lane add: src permuted by CTRL (immediate), then add.
template <int CTRL>
__device__ __forceinline__ float dpp_add(float v) {
  int t = __builtin_amdgcn_mov_dpp(__float_as_int(v), CTRL, 0xF, 0xF, true);
  return v + __int_as_float(t);
}

// Butterfly sum, bitwise-identical to shfl_xor(32,16,8,4,2,1) ladder;
// stages 8/4/2/1 on the VALU DPP path (see R10 notes).
__device__ __forceinline__ float wsum(float v) {
  v += __shfl_xor(v, 32, 64);   // DS (ds_permute)
  v += __shfl_xor(v, 16, 64);   // DS
  v = dpp_add<0x128>(v);        // row_ror:8  -> xor 8
  v = dpp_add<0x124>(v);        // row_ror:4  -> xor 4 (after fold)
  v = dpp_add<0x4E>(v);         // quad_perm [2,3,0,1] -> xor 2
  v = dpp_add<0xB1>(v);         // quad_perm [1,0,3,2] -> xor 1
  return v;
}

__global__ __launch_bounds__(256, 2)
void geo_scramble_kernel(const float* __restrict__ q0g, const float* __restrict__ pdg,
                         const float* __restrict__ W1g, const float* __restrict__ b1g,
                         const float* __restrict__ W2g, const float* __restrict__ b2g,
                         const float* __restrict__ W3g, float* __restrict__ out)
{
  // W2Ts[j][k] : [64][LDW]  (W2Ts[j][k] = W2[k][j]) — LDS (needs both row and
  // column access). W1 lives ONLY in global: it is 32KB = exactly L1-size, so
  // both its phases (L1-fwd coalesced, BW1 divergent-row) are L1-resident and
  // ride the vmem pipe, in parallel with the DS pipe.
  __shared__ __align__(16) float W2Ts[64 * LDW];
  __shared__ __align__(16) float stg_all[4][256];

  const int tid  = threadIdx.x;
  const int lane = tid & 63;
  const int wave = tid >> 6;

  for (int idx = tid; idx < 64 * 128; idx += 256) {
    int j = idx >> 7, k = idx & 127;
    W2Ts[j * LDW + k] = W2g[k * 64 + j];
  }
  __syncthreads();

  const float rb10 = b1g[2 * lane];
  const float rb11 = b1g[2 * lane + 1];
  const float rb2  = b2g[lane];
  const float rw3  = W3g[lane];

  float* stgI = stg_all[wave];
  const int pair = blockIdx.x * 4 + wave;  // one (base, perturbed) pair per wave
  const int l2 = lane << 1;

  float qA = q0g[pair * 64 + lane];
  float qB;
  {
    float qp = qA + 1e-4f * pdg[pair * 64 + lane];
    float n  = sqrtf(wsum(qp * qp));
    float sc = (n > 0.99f) ? (0.99f / (n + EPSV)) : 1.0f;
    qB = qp * sc;
  }
  float pA = 0.0f, pB = 0.0f, gA, gB;

  // Batched gradient of V(q) = W3 . silu(W2 . silu(W1 q + b1) + b2) for the
  // (base, perturbed) pair. Lane j owns latent dim j and hidden dims
  // {2j, 2j+1}. Both trajectories ride each v_pk_fma_f32; per-accumulator
  // FMA order is element-ascending, identical to R10/R11 (bitwise-stable).
  auto evalgrad = [&](float xA, float xB, float& grA, float& grB) {
    {
      f32x2 xx; xx.x = xA; xx.y = xB;
      *(f32x2*)&stgI[l2] = xx;                 // elem=lane pair
    }

    // ---- layer1 forward: z1 = W1^T q + b1 (weights from GLOBAL, coalesced) ----
    f32x2 acc0; acc0.x = rb10; acc0.y = rb10;  // (a0A, a0B)
    f32x2 acc1; acc1.x = rb11; acc1.y = rb11;  // (a1A, a1B)
#pragma unroll 4
    for (int i = 0; i < 64; i += 4) {
      float4 v0 = *(const float4*)&stgI[2 * i];       // elems i, i+1 (A,B pairs)
      float4 v1 = *(const float4*)&stgI[2 * i + 4];   // elems i+2, i+3
      f32x2 p0; p0.x = v0.x; p0.y = v0.y;
      f32x2 p1; p1.x = v0.z; p1.y = v0.w;
      f32x2 p2; p2.x = v1.x; p2.y = v1.y;
      f32x2 p3; p3.x = v1.z; p3.y = v1.w;
      f32x2 w0 = *(const f32x2*)&W1g[(i + 0) * 128 + l2];
      f32x2 w1 = *(const f32x2*)&W1g[(i + 1) * 128 + l2];
      f32x2 w2 = *(const f32x2*)&W1g[(i + 2) * 128 + l2];
      f32x2 w3 = *(const f32x2*)&W1g[(i + 3) * 128 + l2];
      pk_wlo(acc0, p0, w0); pk_whi(acc1, p0, w0);
      pk_wlo(acc0, p1, w1); pk_whi(acc1, p1, w1);
      pk_wlo(acc0, p2, w2); pk_whi(acc1, p2, w2);
      pk_wlo(acc0, p3, w3); pk_whi(acc1, p3, w3);
    }

    // silu + derivative (scalar, identical op sequence); stage h interleaved
    float a0A = acc0.x, a0B = acc0.y, a1A = acc1.x, a1B = acc1.y;
    float sA0 = 1.0f / (1.0f + expf(-a0A));
    float h0A = a0A * sA0;
    float d10A = sA0 * (1.0f + a0A * (1.0f - sA0));
    float sA1 = 1.0f / (1.0f + expf(-a1A));
    float h1A = a1A * sA1;
    float d11A = sA1 * (1.0f + a1A * (1.0f - sA1));
    float sB0 = 1.0f / (1.0f + expf(-a0B));
    float h0B = a0B * sB0;
    float d10B = sB0 * (1.0f + a0B * (1.0f - sB0));
    float sB1 = 1.0f / (1.0f + expf(-a1B));
    float h1B = a1B * sB1;
    float d11B = sB1 * (1.0f + a1B * (1.0f - sB1));
    {
      float4 hh; hh.x = h0A; hh.y = h0B; hh.z = h1A; hh.w = h1B;
      *(float4*)&stgI[4 * lane] = hh;          // elems 2l, 2l+1 pairs
    }

    // ---- layer2 forward: z2 = W2^T h1 + b2 (W2T rows from LDS) ----
    f32x2 acc2; acc2.x = rb2; acc2.y = rb2;    // (a2A, a2B)
#pragma unroll 8
    for (int k = 0; k < 128; k += 4) {
      float4 v0 = *(const float4*)&stgI[2 * k];
      float4 v1 = *(const float4*)&stgI[2 * k + 4];
      f32x2 p0; p0.x = v0.x; p0.y = v0.y;
      f32x2 p1; p1.x = v0.z; p1.y = v0.w;
      f32x2 p2; p2.x = v1.x; p2.y = v1.y;
      f32x2 p3; p3.x = v1.z; p3.y = v1.w;
      float4 w4 = *(const float4*)&W2Ts[lane * LDW + k];
      f32x2 w01; w01.x = w4.x; w01.y = w4.y;
      f32x2 w23; w23.x = w4.z; w23.y = w4.w;
      pk_wlo(acc2, p0, w01);   // += h[k]   * w4.x
      pk_whi(acc2, p1, w01);   // += h[k+1] * w4.y
      pk_wlo(acc2, p2, w23);   // += h[k+2] * w4.z
      pk_whi(acc2, p3, w23);   // += h[k+3] * w4.w
    }

    // g2 = W3 * silu'(z2); stage interleaved
    {
      float a2A = acc2.x, a2B = acc2.y;
      float t2A = 1.0f / (1.0f + expf(-a2A));
      float g2A = rw3 * (t2A * (1.0f + a2A * (1.0f - t2A)));
      float t2B = 1.0f / (1.0f + expf(-a2B));
      float g2B = rw3 * (t2B * (1.0f + a2B * (1.0f - t2B)));
      f32x2 gg; gg.x = g2A; gg.y = g2B;
      *(f32x2*)&stgI[l2] = gg;
    }

    // ---- backward through W2: gh1[k] = sum_j g2[j] * W2[k][j] (LDS columns) ----
    f32x2 c0; c0.x = 0.0f; c0.y = 0.0f;        // (c0A, c0B)
    f32x2 c1; c1.x = 0.0f; c1.y = 0.0f;        // (c1A, c1B)
#pragma unroll 4
    for (int j = 0; j < 64; j += 4) {
      float4 v0 = *(const float4*)&stgI[2 * j];
      float4 v1 = *(const float4*)&stgI[2 * j + 4];
      f32x2 p0; p0.x = v0.x; p0.y = v0.y;
      f32x2 p1; p1.x = v0.z; p1.y = v0.w;
      f32x2 p2; p2.x = v1.x; p2.y = v1.y;
      f32x2 p3; p3.x = v1.z; p3.y = v1.w;
      f32x2 w0 = *(const f32x2*)&W2Ts[(j + 0) * LDW + l2];
      f32x2 w1 = *(const f32x2*)&W2Ts[(j + 1) * LDW + l2];
      f32x2 w2 = *(const f32x2*)&W2Ts[(j + 2) * LDW + l2];
      f32x2 w3 = *(const f32x2*)&W2Ts[(j + 3) * LDW + l2];
      pk_wlo(c0, p0, w0); pk_whi(c1, p0, w0);
      pk_wlo(c0, p1, w1); pk_whi(c1, p1, w1);
      pk_wlo(c0, p2, w2); pk_whi(c1, p2, w2);
      pk_wlo(c0, p3, w3); pk_whi(c1, p3, w3);
    }

    // g1 = gh1 * silu'(z1); stage interleaved
    {
      float4 gg;
      gg.x = c0.x * d10A; gg.y = c0.y * d10B;
      gg.z = c1.x * d11A; gg.w = c1.y * d11B;
      *(float4*)&stgI[4 * lane] = gg;
    }

    // ---- backward through W1: grad[i] = sum_k g1[k] * W1[i][k] ----
    // Lane reads its own W1 row from GLOBAL (contiguous b128; W1 = 32KB is
    // fully L1-resident since no other global stream competes).
    f32x2 gr; gr.x = 0.0f; gr.y = 0.0f;        // (grA, grB)
#pragma unroll 8
    for (int k = 0; k < 128; k += 4) {
      float4 v0 = *(const float4*)&stgI[2 * k];
      float4 v1 = *(const float4*)&stgI[2 * k + 4];
      f32x2 p0; p0.x = v0.x; p0.y = v0.y;
      f32x2 p1; p1.x = v0.z; p1.y = v0.w;
      f32x2 p2; p2.x = v1.x; p2.y = v1.y;
      f32x2 p3; p3.x = v1.z; p3.y = v1.w;
      float4 w4 = *(const float4*)&W1g[lane * 128 + k];
      f32x2 w01; w01.x = w4.x; w01.y = w4.y;
      f32x2 w23; w23.x = w4.z; w23.y = w4.w;
      pk_wlo(gr, p0, w01);
      pk_whi(gr, p1, w01);
      pk_wlo(gr, p2, w23);
      pk_whi(gr, p3, w23);
    }
    grA = gr.x; grB = gr.y;
  };

  evalgrad(qA, qB, gA, gB);  // gradV at initial positions

  for (int s = 0; s < STEPS; ++s) {
    // wsum(q·q) computed once per trajectory, shared bitwise between the
    // distance and the leapfrog (identical expression on identical bits).
    float qq0 = wsum(qA * qA);
    float qq1 = wsum(qB * qB);

    // distance BEFORE leapfrog (matches scan order)
    {
      float df = qA - qB;
      float d2 = wsum(df * df);
      float x2 = fminf(qq0, 0.999f);
      float y2 = fminf(qq1, 0.999f);
      float arg = 1.0f + 2.0f * d2 / ((1.0f - x2) * (1.0f - y2) + EPSV);
      float d = acoshf(fmaxf(arg, 1.0f + EPSV));
      if (lane == 0) out[s * BATCH + pair] = d;
    }

    // leapfrog first half, trajectory A (R10 op sequence, unchanged)
    float qnA, phA;
    {
      float ph  = (pA - 0.5f * DT * gA) * (1.0f - DAMP);
      float q2r = qq0;
      float q2c = fminf(q2r, 0.999f);
      float lam = 2.0f / (1.0f - q2c);
      float v   = DT * ph / (lam * lam);
      float vn  = sqrtf(wsum(v * v)) + EPSV;
      float mag = tanhf(fminf(lam * vn * 0.5f, 15.0f));
      float y   = mag * (v / vn);
      float y2  = wsum(y * y);
      float xy  = wsum(qA * y);
      float num = (1.0f + 2.0f * xy + y2) * qA + (1.0f - q2r) * y;
      float den = 1.0f + 2.0f * xy + q2r * y2;
      float r   = num / (den + EPSV);
      float rn  = sqrtf(wsum(r * r));
      float sc  = (rn > 0.99f) ? (0.99f / (rn + EPSV)) : 1.0f;
      qnA = r * sc;
      phA = ph;
    }
    // leapfrog first half, trajectory B
    float qnB, phB;
    {
      float ph  = (pB - 0.5f * DT * gB) * (1.0f - DAMP);
      float q2r = qq1;
      float q2c = fminf(q2r, 0.999f);
      float lam = 2.0f / (1.0f - q2c);
      float v   = DT * ph / (lam * lam);
      float vn  = sqrtf(wsum(v * v)) + EPSV;
      float mag = tanhf(fminf(lam * vn * 0.5f, 15.0f));
      float y   = mag * (v / vn);
      float y2  = wsum(y * y);
      float xy  = wsum(qB * y);
      float num = (1.0f + 2.0f * xy + y2) * qB + (1.0f - q2r) * y;
      float den = 1.0f + 2.0f * xy + q2r * y2;
      float r   = num / (den + EPSV);
      float rn  = sqrtf(wsum(r * r));
      float sc  = (rn > 0.99f) ? (0.99f / (rn + EPSV)) : 1.0f;
      qnB = r * sc;
      phB = ph;
    }

    evalgrad(qnA, qnB, gA, gB);  // gradV(q_new); reused as next step's gradV(q)

    pA = phA - 0.5f * DT * gA; qA = qnA;
    pB = phB - 0.5f * DT * gB; qB = qnB;
  }
}

}  // namespace

extern "C" void kernel_launch(void* const* d_in, const int* in_sizes, int n_in,
                              void* d_out, int out_size, void* d_ws, size_t ws_size,
                              hipStream_t stream) {
  (void)in_sizes; (void)n_in; (void)out_size; (void)d_ws; (void)ws_size;
  const float* q0 = (const float*)d_in[0];
  const float* pd = (const float*)d_in[1];
  const float* W1 = (const float*)d_in[2];
  const float* b1 = (const float*)d_in[3];
  const float* W2 = (const float*)d_in[4];
  const float* b2 = (const float*)d_in[5];
  const float* W3 = (const float*)d_in[6];
  // d_in[7] = b3: constant offset, does not affect gradV or distances.
  float* out = (float*)d_out;

  geo_scramble_kernel<<<dim3(512), dim3(256), 0, stream>>>(q0, pd, W1, b1, W2, b2, W3, out);
}

// Round 14
// 841.986 us; speedup vs baseline: 1.4489x; 1.4489x over previous
//
#include <hip/hip_runtime.h>
#include <math.h>

namespace {

constexpr int   STEPS = 100;
constexpr int   BATCH = 2048;
constexpr float DT    = 0.05f;
constexpr float DAMP  = 0.01f;
constexpr float EPSV  = 1e-8f;
constexpr int   LDW   = 130; // R2-proven stride (0 conflicts measured)

typedef float f32x2 __attribute__((ext_vector_type(2)));

// Dual FP32 FMA (one VOP3P issue). acc.lo += s.lo*w.SEL; acc.hi += s.hi*w.SEL.
// Weight-half replication via op_sel (no splat movs). Each half is an exact
// IEEE FMA -> bitwise-identical to the scalar fmaf pair it replaces.
__device__ __forceinline__ void pk_wlo(f32x2& acc, f32x2 s, f32x2 w) {
  asm("v_pk_fma_f32 %0, %1, %2, %0 op_sel:[0,0,0] op_sel_hi:[1,0,1]"
      : "+v"(acc) : "v"(s), "v"(w));
}
__device__ __forceinline__ void pk_whi(f32x2& acc, f32x2 s, f32x2 w) {
  asm("v_pk_fma_f32 %0, %1, %2, %0 op_sel:[0,1,0] op_sel_hi:[1,1,1]"
      : "+v"(acc) : "v"(s), "v"(w));
}

// DPP-assisted cross-lane add: src permuted by CTRL (immediate), then add.
template <int CTRL>
__device__ __forceinline__ float dpp_add(float v) {
  int t = __builtin_amdgcn_mov_dpp(__float_as_int(v), CTRL, 0xF, 0xF, true);
  return v + __int_as_float(t);
}

// Butterfly sum, bitwise-identical to the shfl_xor(32,16,8,4,2,1) ladder,
// now fully DS-pipe-free:
//   xor-32/16 via gfx950 v_permlane{32,16}_swap (VALU): with both operands
//   = v, the result pair is {low-half-broadcast, high-half-broadcast}, so
//   r[0]+r[1] == v[l] + v[l^K] for every lane (IEEE add commutes bitwise);
//   xor-8/4/2/1 via DPP (R10-proven on HW).
__device__ __forceinline__ float wsum(float v) {
  {
    unsigned u = __float_as_uint(v);
    auto r = __builtin_amdgcn_permlane32_swap(u, u, false, false);
    v = __uint_as_float(r[0]) + __uint_as_float(r[1]);
  }
  {
    unsigned u = __float_as_uint(v);
    auto r = __builtin_amdgcn_permlane16_swap(u, u, false, false);
    v = __uint_as_float(r[0]) + __uint_as_float(r[1]);
  }
  v = dpp_add<0x128>(v);        // row_ror:8  -> xor 8
  v = dpp_add<0x124>(v);        // row_ror:4  -> xor 4 (after fold)
  v = dpp_add<0x4E>(v);         // quad_perm [2,3,0,1] -> xor 2
  v = dpp_add<0xB1>(v);         // quad_perm [1,0,3,2] -> xor 1
  return v;
}

__global__ __launch_bounds__(256, 2)
void geo_scramble_kernel(const float* __restrict__ q0g, const float* __restrict__ pdg,
                         const float* __restrict__ W1g, const float* __restrict__ b1g,
                         const float* __restrict__ W2g, const float* __restrict__ b2g,
                         const float* __restrict__ W3g, float* __restrict__ out)
{
  // W1s[i][h] : [64][LDW]   W2Ts[j][k] : [64][LDW]  (W2Ts[j][k] = W2[k][j])
  // L1-fwd weights come straight from global (coalesced, L1-resident);
  // divergent weight phases (L2fwd/BW2 via W2Ts, BW1 via W1s) stay in LDS
  // (R12 measured: divergent global rows cost -40%).
  __shared__ __align__(16) float W1s[64 * LDW];
  __shared__ __align__(16) float W2Ts[64 * LDW];
  __shared__ __align__(16) float stg_all[4][256];

  const int tid  = threadIdx.x;
  const int lane = tid & 63;
  const int wave = tid >> 6;

  for (int idx = tid; idx < 64 * 128; idx += 256) {
    int r = idx >> 7, c = idx & 127;
    W1s[r * LDW + c] = W1g[idx];
  }
  for (int idx = tid; idx < 64 * 128; idx += 256) {
    int j = idx >> 7, k = idx & 127;
    W2Ts[j * LDW + k] = W2g[k * 64 + j];
  }
  __syncthreads();

  const float rb10 = b1g[2 * lane];
  const float rb11 = b1g[2 * lane + 1];
  const float rb2  = b2g[lane];
  const float rw3  = W3g[lane];

  float* stgI = stg_all[wave];
  const int pair = blockIdx.x * 4 + wave;  // one (base, perturbed) pair per wave
  const int l2 = lane << 1;

  float qA = q0g[pair * 64 + lane];
  float qB;
  {
    float qp = qA + 1e-4f * pdg[pair * 64 + lane];
    float n  = sqrtf(wsum(qp * qp));
    float sc = (n > 0.99f) ? (0.99f / (n + EPSV)) : 1.0f;
    qB = qp * sc;
  }
  float pA = 0.0f, pB = 0.0f, gA, gB;

  // Batched gradient of V(q) = W3 . silu(W2 . silu(W1 q + b1) + b2) for the
  // (base, perturbed) pair. Lane j owns latent dim j and hidden dims
  // {2j, 2j+1}. Both trajectories ride each v_pk_fma_f32; per-accumulator
  // FMA order is element-ascending, identical to R10/R11 (bitwise-stable).
  auto evalgrad = [&](float xA, float xB, float& grA, float& grB) {
    {
      f32x2 xx; xx.x = xA; xx.y = xB;
      *(f32x2*)&stgI[l2] = xx;                 // elem=lane pair
    }

    // ---- layer1 forward: z1 = W1^T q + b1 (weights from GLOBAL, coalesced) ----
    f32x2 acc0; acc0.x = rb10; acc0.y = rb10;  // (a0A, a0B)
    f32x2 acc1; acc1.x = rb11; acc1.y = rb11;  // (a1A, a1B)
#pragma unroll 4
    for (int i = 0; i < 64; i += 4) {
      float4 v0 = *(const float4*)&stgI[2 * i];       // elems i, i+1 (A,B pairs)
      float4 v1 = *(const float4*)&stgI[2 * i + 4];   // elems i+2, i+3
      f32x2 p0; p0.x = v0.x; p0.y = v0.y;
      f32x2 p1; p1.x = v0.z; p1.y = v0.w;
      f32x2 p2; p2.x = v1.x; p2.y = v1.y;
      f32x2 p3; p3.x = v1.z; p3.y = v1.w;
      f32x2 w0 = *(const f32x2*)&W1g[(i + 0) * 128 + l2];
      f32x2 w1 = *(const f32x2*)&W1g[(i + 1) * 128 + l2];
      f32x2 w2 = *(const f32x2*)&W1g[(i + 2) * 128 + l2];
      f32x2 w3 = *(const f32x2*)&W1g[(i + 3) * 128 + l2];
      pk_wlo(acc0, p0, w0); pk_whi(acc1, p0, w0);
      pk_wlo(acc0, p1, w1); pk_whi(acc1, p1, w1);
      pk_wlo(acc0, p2, w2); pk_whi(acc1, p2, w2);
      pk_wlo(acc0, p3, w3); pk_whi(acc1, p3, w3);
    }

    // silu + derivative (scalar, identical op sequence); stage h interleaved
    float a0A = acc0.x, a0B = acc0.y, a1A = acc1.x, a1B = acc1.y;
    float sA0 = 1.0f / (1.0f + expf(-a0A));
    float h0A = a0A * sA0;
    float d10A = sA0 * (1.0f + a0A * (1.0f - sA0));
    float sA1 = 1.0f / (1.0f + expf(-a1A));
    float h1A = a1A * sA1;
    float d11A = sA1 * (1.0f + a1A * (1.0f - sA1));
    float sB0 = 1.0f / (1.0f + expf(-a0B));
    float h0B = a0B * sB0;
    float d10B = sB0 * (1.0f + a0B * (1.0f - sB0));
    float sB1 = 1.0f / (1.0f + expf(-a1B));
    float h1B = a1B * sB1;
    float d11B = sB1 * (1.0f + a1B * (1.0f - sB1));
    {
      float4 hh; hh.x = h0A; hh.y = h0B; hh.z = h1A; hh.w = h1B;
      *(float4*)&stgI[4 * lane] = hh;          // elems 2l, 2l+1 pairs
    }

    // ---- layer2 forward: z2 = W2^T h1 + b2 (W2T rows from LDS) ----
    f32x2 acc2; acc2.x = rb2; acc2.y = rb2;    // (a2A, a2B)
#pragma unroll 8
    for (int k = 0; k < 128; k += 4) {
      float4 v0 = *(const float4*)&stgI[2 * k];
      float4 v1 = *(const float4*)&stgI[2 * k + 4];
      f32x2 p0; p0.x = v0.x; p0.y = v0.y;
      f32x2 p1; p1.x = v0.z; p1.y = v0.w;
      f32x2 p2; p2.x = v1.x; p2.y = v1.y;
      f32x2 p3; p3.x = v1.z; p3.y = v1.w;
      float4 w4 = *(const float4*)&W2Ts[lane * LDW + k];
      f32x2 w01; w01.x = w4.x; w01.y = w4.y;
      f32x2 w23; w23.x = w4.z; w23.y = w4.w;
      pk_wlo(acc2, p0, w01);   // += h[k]   * w4.x
      pk_whi(acc2, p1, w01);   // += h[k+1] * w4.y
      pk_wlo(acc2, p2, w23);   // += h[k+2] * w4.z
      pk_whi(acc2, p3, w23);   // += h[k+3] * w4.w
    }

    // g2 = W3 * silu'(z2); stage interleaved
    {
      float a2A = acc2.x, a2B = acc2.y;
      float t2A = 1.0f / (1.0f + expf(-a2A));
      float g2A = rw3 * (t2A * (1.0f + a2A * (1.0f - t2A)));
      float t2B = 1.0f / (1.0f + expf(-a2B));
      float g2B = rw3 * (t2B * (1.0f + a2B * (1.0f - t2B)));
      f32x2 gg; gg.x = g2A; gg.y = g2B;
      *(f32x2*)&stgI[l2] = gg;
    }

    // ---- backward through W2: gh1[k] = sum_j g2[j] * W2[k][j] (LDS columns) ----
    f32x2 c0; c0.x = 0.0f; c0.y = 0.0f;        // (c0A, c0B)
    f32x2 c1; c1.x = 0.0f; c1.y = 0.0f;        // (c1A, c1B)
#pragma unroll 4
    for (int j = 0; j < 64; j += 4) {
      float4 v0 = *(const float4*)&stgI[2 * j];
      float4 v1 = *(const float4*)&stgI[2 * j + 4];
      f32x2 p0; p0.x = v0.x; p0.y = v0.y;
      f32x2 p1; p1.x = v0.z; p1.y = v0.w;
      f32x2 p2; p2.x = v1.x; p2.y = v1.y;
      f32x2 p3; p3.x = v1.z; p3.y = v1.w;
      f32x2 w0 = *(const f32x2*)&W2Ts[(j + 0) * LDW + l2];
      f32x2 w1 = *(const f32x2*)&W2Ts[(j + 1) * LDW + l2];
      f32x2 w2 = *(const f32x2*)&W2Ts[(j + 2) * LDW + l2];
      f32x2 w3 = *(const f32x2*)&W2Ts[(j + 3) * LDW + l2];
      pk_wlo(c0, p0, w0); pk_whi(c1, p0, w0);
      pk_wlo(c0, p1, w1); pk_whi(c1, p1, w1);
      pk_wlo(c0, p2, w2); pk_whi(c1, p2, w2);
      pk_wlo(c0, p3, w3); pk_whi(c1, p3, w3);
    }

    // g1 = gh1 * silu'(z1); stage interleaved
    {
      float4 gg;
      gg.x = c0.x * d10A; gg.y = c0.y * d10B;
      gg.z = c1.x * d11A; gg.w = c1.y * d11B;
      *(float4*)&stgI[4 * lane] = gg;
    }

    // ---- backward through W1: grad[i] = sum_k g1[k] * W1[i][k] (LDS rows) ----
    f32x2 gr; gr.x = 0.0f; gr.y = 0.0f;        // (grA, grB)
#pragma unroll 8
    for (int k = 0; k < 128; k += 4) {
      float4 v0 = *(const float4*)&stgI[2 * k];
      float4 v1 = *(const float4*)&stgI[2 * k + 4];
      f32x2 p0; p0.x = v0.x; p0.y = v0.y;
      f32x2 p1; p1.x = v0.z; p1.y = v0.w;
      f32x2 p2; p2.x = v1.x; p2.y = v1.y;
      f32x2 p3; p3.x = v1.z; p3.y = v1.w;
      float4 w4 = *(const float4*)&W1s[lane * LDW + k];
      f32x2 w01; w01.x = w4.x; w01.y = w4.y;
      f32x2 w23; w23.x = w4.z; w23.y = w4.w;
      pk_wlo(gr, p0, w01);
      pk_whi(gr, p1, w01);
      pk_wlo(gr, p2, w23);
      pk_whi(gr, p3, w23);
    }
    grA = gr.x; grB = gr.y;
  };

  evalgrad(qA, qB, gA, gB);  // gradV at initial positions

  for (int s = 0; s < STEPS; ++s) {
    // wsum(q·q) computed once per trajectory, shared bitwise between the
    // distance and the leapfrog (identical expression on identical bits).
    float qq0 = wsum(qA * qA);
    float qq1 = wsum(qB * qB);

    // distance BEFORE leapfrog (matches scan order)
    {
      float df = qA - qB;
      float d2 = wsum(df * df);
      float x2 = fminf(qq0, 0.999f);
      float y2 = fminf(qq1, 0.999f);
      float arg = 1.0f + 2.0f * d2 / ((1.0f - x2) * (1.0f - y2) + EPSV);
      float d = acoshf(fmaxf(arg, 1.0f + EPSV));
      if (lane == 0) out[s * BATCH + pair] = d;
    }

    // leapfrog first half, trajectory A (R10 op sequence, unchanged)
    float qnA, phA;
    {
      float ph  = (pA - 0.5f * DT * gA) * (1.0f - DAMP);
      float q2r = qq0;
      float q2c = fminf(q2r, 0.999f);
      float lam = 2.0f / (1.0f - q2c);
      float v   = DT * ph / (lam * lam);
      float vn  = sqrtf(wsum(v * v)) + EPSV;
      float mag = tanhf(fminf(lam * vn * 0.5f, 15.0f));
      float y   = mag * (v / vn);
      float y2  = wsum(y * y);
      float xy  = wsum(qA * y);
      float num = (1.0f + 2.0f * xy + y2) * qA + (1.0f - q2r) * y;
      float den = 1.0f + 2.0f * xy + q2r * y2;
      float r   = num / (den + EPSV);
      float rn  = sqrtf(wsum(r * r));
      float sc  = (rn > 0.99f) ? (0.99f / (rn + EPSV)) : 1.0f;
      qnA = r * sc;
      phA = ph;
    }
    // leapfrog first half, trajectory B
    float qnB, phB;
    {
      float ph  = (pB - 0.5f * DT * gB) * (1.0f - DAMP);
      float q2r = qq1;
      float q2c = fminf(q2r, 0.999f);
      float lam = 2.0f / (1.0f - q2c);
      float v   = DT * ph / (lam * lam);
      float vn  = sqrtf(wsum(v * v)) + EPSV;
      float mag = tanhf(fminf(lam * vn * 0.5f, 15.0f));
      float y   = mag * (v / vn);
      float y2  = wsum(y * y);
      float xy  = wsum(qB * y);
      float num = (1.0f + 2.0f * xy + y2) * qB + (1.0f - q2r) * y;
      float den = 1.0f + 2.0f * xy + q2r * y2;
      float r   = num / (den + EPSV);
      float rn  = sqrtf(wsum(r * r));
      float sc  = (rn > 0.99f) ? (0.99f / (rn + EPSV)) : 1.0f;
      qnB = r * sc;
      phB = ph;
    }

    evalgrad(qnA, qnB, gA, gB);  // gradV(q_new); reused as next step's gradV(q)

    pA = phA - 0.5f * DT * gA; qA = qnA;
    pB = phB - 0.5f * DT * gB; qB = qnB;
  }
}

}  // namespace

extern "C" void kernel_launch(void* const* d_in, const int* in_sizes, int n_in,
                              void* d_out, int out_size, void* d_ws, size_t ws_size,
                              hipStream_t stream) {
  (void)in_sizes; (void)n_in; (void)out_size; (void)d_ws; (void)ws_size;
  const float* q0 = (const float*)d_in[0];
  const float* pd = (const float*)d_in[1];
  const float* W1 = (const float*)d_in[2];
  const float* b1 = (const float*)d_in[3];
  const float* W2 = (const float*)d_in[4];
  const float* b2 = (const float*)d_in[5];
  const float* W3 = (const float*)d_in[6];
  // d_in[7] = b3: constant offset, does not affect gradV or distances.
  float* out = (float*)d_out;

  geo_scramble_kernel<<<dim3(512), dim3(256), 0, stream>>>(q0, pd, W1, b1, W2, b2, W3, out);
}

// Round 15
// 836.855 us; speedup vs baseline: 1.4578x; 1.0061x over previous
//
#include <hip/hip_runtime.h>
#include <math.h>

namespace {

constexpr int   STEPS = 100;
constexpr int   BATCH = 2048;
constexpr float DT    = 0.05f;
constexpr float DAMP  = 0.01f;
constexpr float EPSV  = 1e-8f;
constexpr int   LDW   = 130; // R2-proven stride (0 conflicts measured)

typedef float f32x2 __attribute__((ext_vector_type(2)));

// Dual FP32 FMA (one VOP3P issue). acc.lo += s.lo*w.SEL; acc.hi += s.hi*w.SEL.
// Weight-half replication via op_sel (no splat movs). Each half is an exact
// IEEE FMA -> bitwise-identical to the scalar fmaf pair it replaces.
__device__ __forceinline__ void pk_wlo(f32x2& acc, f32x2 s, f32x2 w) {
  asm("v_pk_fma_f32 %0, %1, %2, %0 op_sel:[0,0,0] op_sel_hi:[1,0,1]"
      : "+v"(acc) : "v"(s), "v"(w));
}
__device__ __forceinline__ void pk_whi(f32x2& acc, f32x2 s, f32x2 w) {
  asm("v_pk_fma_f32 %0, %1, %2, %0 op_sel:[0,1,0] op_sel_hi:[1,1,1]"
      : "+v"(acc) : "v"(s), "v"(w));
}

// DPP-assisted cross-lane add: src permuted by CTRL (immediate), then add.
template <int CTRL>
__device__ __forceinline__ float dpp_add(float v) {
  int t = __builtin_amdgcn_mov_dpp(__float_as_int(v), CTRL, 0xF, 0xF, true);
  return v + __int_as_float(t);
}

// Butterfly sum, bitwise-identical to the shfl_xor(32,16,8,4,2,1) ladder,
// fully DS-pipe-free (R14-proven on HW):
//   xor-32/16 via gfx950 v_permlane{32,16}_swap (VALU);
//   xor-8/4/2/1 via DPP.
__device__ __forceinline__ float wsum(float v) {
  {
    unsigned u = __float_as_uint(v);
    auto r = __builtin_amdgcn_permlane32_swap(u, u, false, false);
    v = __uint_as_float(r[0]) + __uint_as_float(r[1]);
  }
  {
    unsigned u = __float_as_uint(v);
    auto r = __builtin_amdgcn_permlane16_swap(u, u, false, false);
    v = __uint_as_float(r[0]) + __uint_as_float(r[1]);
  }
  v = dpp_add<0x128>(v);        // row_ror:8  -> xor 8
  v = dpp_add<0x124>(v);        // row_ror:4  -> xor 4 (after fold)
  v = dpp_add<0x4E>(v);         // quad_perm [2,3,0,1] -> xor 2
  v = dpp_add<0xB1>(v);         // quad_perm [1,0,3,2] -> xor 1
  return v;
}

__global__ __launch_bounds__(256, 2)
void geo_scramble_kernel(const float* __restrict__ q0g, const float* __restrict__ pdg,
                         const float* __restrict__ W1g, const float* __restrict__ b1g,
                         const float* __restrict__ W2g, const float* __restrict__ b2g,
                         const float* __restrict__ W3g, float* __restrict__ out)
{
  // W1s[i][h] : [64][LDW]   W2Ts[j][k] : [64][LDW]  (W2Ts[j][k] = W2[k][j])
  // L1-fwd weights come straight from global (coalesced, L1-resident);
  // divergent weight phases (L2fwd/BW2 via W2Ts, BW1 via W1s) stay in LDS
  // (R12 measured: divergent global rows cost -40%).
  __shared__ __align__(16) float W1s[64 * LDW];
  __shared__ __align__(16) float W2Ts[64 * LDW];
  __shared__ __align__(16) float stg_all[4][256];

  const int tid  = threadIdx.x;
  const int lane = tid & 63;
  const int wave = tid >> 6;

  for (int idx = tid; idx < 64 * 128; idx += 256) {
    int r = idx >> 7, c = idx & 127;
    W1s[r * LDW + c] = W1g[idx];
  }
  for (int idx = tid; idx < 64 * 128; idx += 256) {
    int j = idx >> 7, k = idx & 127;
    W2Ts[j * LDW + k] = W2g[k * 64 + j];
  }
  __syncthreads();

  const float rb10 = b1g[2 * lane];
  const float rb11 = b1g[2 * lane + 1];
  const float rb2  = b2g[lane];
  const float rw3  = W3g[lane];

  float* stgI = stg_all[wave];
  const int pair = blockIdx.x * 4 + wave;  // one (base, perturbed) pair per wave
  const int l2 = lane << 1;

  float qA = q0g[pair * 64 + lane];
  float qB;
  {
    float qp = qA + 1e-4f * pdg[pair * 64 + lane];
    float n  = sqrtf(wsum(qp * qp));
    float sc = (n > 0.99f) ? (0.99f / (n + EPSV)) : 1.0f;
    qB = qp * sc;
  }
  float pA = 0.0f, pB = 0.0f, gA, gB;

  // Batched gradient of V(q) = W3 . silu(W2 . silu(W1 q + b1) + b2) for the
  // (base, perturbed) pair. Lane j owns latent dim j and hidden dims
  // {2j, 2j+1}. Both trajectories ride each v_pk_fma_f32; per-accumulator
  // FMA order is element-ascending, identical to R10-R14 (bitwise-stable).
  auto evalgrad = [&](float xA, float xB, float& grA, float& grB) {
    {
      f32x2 xx; xx.x = xA; xx.y = xB;
      *(f32x2*)&stgI[l2] = xx;                 // elem=lane pair
    }

    // ---- layer1 forward: z1 = W1^T q + b1 (weights from GLOBAL, coalesced) ----
    f32x2 acc0; acc0.x = rb10; acc0.y = rb10;  // (a0A, a0B)
    f32x2 acc1; acc1.x = rb11; acc1.y = rb11;  // (a1A, a1B)
#pragma unroll 4
    for (int i = 0; i < 64; i += 4) {
      float4 v0 = *(const float4*)&stgI[2 * i];       // elems i, i+1 (A,B pairs)
      float4 v1 = *(const float4*)&stgI[2 * i + 4];   // elems i+2, i+3
      f32x2 p0; p0.x = v0.x; p0.y = v0.y;
      f32x2 p1; p1.x = v0.z; p1.y = v0.w;
      f32x2 p2; p2.x = v1.x; p2.y = v1.y;
      f32x2 p3; p3.x = v1.z; p3.y = v1.w;
      f32x2 w0 = *(const f32x2*)&W1g[(i + 0) * 128 + l2];
      f32x2 w1 = *(const f32x2*)&W1g[(i + 1) * 128 + l2];
      f32x2 w2 = *(const f32x2*)&W1g[(i + 2) * 128 + l2];
      f32x2 w3 = *(const f32x2*)&W1g[(i + 3) * 128 + l2];
      pk_wlo(acc0, p0, w0); pk_whi(acc1, p0, w0);
      pk_wlo(acc0, p1, w1); pk_whi(acc1, p1, w1);
      pk_wlo(acc0, p2, w2); pk_whi(acc1, p2, w2);
      pk_wlo(acc0, p3, w3); pk_whi(acc1, p3, w3);
    }

    // silu + derivative (scalar, identical op sequence); stage h interleaved
    float a0A = acc0.x, a0B = acc0.y, a1A = acc1.x, a1B = acc1.y;
    float sA0 = 1.0f / (1.0f + expf(-a0A));
    float h0A = a0A * sA0;
    float d10A = sA0 * (1.0f + a0A * (1.0f - sA0));
    float sA1 = 1.0f / (1.0f + expf(-a1A));
    float h1A = a1A * sA1;
    float d11A = sA1 * (1.0f + a1A * (1.0f - sA1));
    float sB0 = 1.0f / (1.0f + expf(-a0B));
    float h0B = a0B * sB0;
    float d10B = sB0 * (1.0f + a0B * (1.0f - sB0));
    float sB1 = 1.0f / (1.0f + expf(-a1B));
    float h1B = a1B * sB1;
    float d11B = sB1 * (1.0f + a1B * (1.0f - sB1));
    {
      float4 hh; hh.x = h0A; hh.y = h0B; hh.z = h1A; hh.w = h1B;
      *(float4*)&stgI[4 * lane] = hh;          // elems 2l, 2l+1 pairs
    }

    // ---- layer2 forward: z2 = W2^T h1 + b2 (W2T rows from LDS) ----
    f32x2 acc2; acc2.x = rb2; acc2.y = rb2;    // (a2A, a2B)
#pragma unroll 8
    for (int k = 0; k < 128; k += 4) {
      float4 v0 = *(const float4*)&stgI[2 * k];
      float4 v1 = *(const float4*)&stgI[2 * k + 4];
      f32x2 p0; p0.x = v0.x; p0.y = v0.y;
      f32x2 p1; p1.x = v0.z; p1.y = v0.w;
      f32x2 p2; p2.x = v1.x; p2.y = v1.y;
      f32x2 p3; p3.x = v1.z; p3.y = v1.w;
      float4 w4 = *(const float4*)&W2Ts[lane * LDW + k];
      f32x2 w01; w01.x = w4.x; w01.y = w4.y;
      f32x2 w23; w23.x = w4.z; w23.y = w4.w;
      pk_wlo(acc2, p0, w01);   // += h[k]   * w4.x
      pk_whi(acc2, p1, w01);   // += h[k+1] * w4.y
      pk_wlo(acc2, p2, w23);   // += h[k+2] * w4.z
      pk_whi(acc2, p3, w23);   // += h[k+3] * w4.w
    }

    // g2 = W3 * silu'(z2); stage interleaved
    {
      float a2A = acc2.x, a2B = acc2.y;
      float t2A = 1.0f / (1.0f + expf(-a2A));
      float g2A = rw3 * (t2A * (1.0f + a2A * (1.0f - t2A)));
      float t2B = 1.0f / (1.0f + expf(-a2B));
      float g2B = rw3 * (t2B * (1.0f + a2B * (1.0f - t2B)));
      f32x2 gg; gg.x = g2A; gg.y = g2B;
      *(f32x2*)&stgI[l2] = gg;
    }

    // ---- backward through W2: gh1[k] = sum_j g2[j] * W2[k][j] (LDS columns) ----
    f32x2 c0; c0.x = 0.0f; c0.y = 0.0f;        // (c0A, c0B)
    f32x2 c1; c1.x = 0.0f; c1.y = 0.0f;        // (c1A, c1B)
#pragma unroll 4
    for (int j = 0; j < 64; j += 4) {
      float4 v0 = *(const float4*)&stgI[2 * j];
      float4 v1 = *(const float4*)&stgI[2 * j + 4];
      f32x2 p0; p0.x = v0.x; p0.y = v0.y;
      f32x2 p1; p1.x = v0.z; p1.y = v0.w;
      f32x2 p2; p2.x = v1.x; p2.y = v1.y;
      f32x2 p3; p3.x = v1.z; p3.y = v1.w;
      f32x2 w0 = *(const f32x2*)&W2Ts[(j + 0) * LDW + l2];
      f32x2 w1 = *(const f32x2*)&W2Ts[(j + 1) * LDW + l2];
      f32x2 w2 = *(const f32x2*)&W2Ts[(j + 2) * LDW + l2];
      f32x2 w3 = *(const f32x2*)&W2Ts[(j + 3) * LDW + l2];
      pk_wlo(c0, p0, w0); pk_whi(c1, p0, w0);
      pk_wlo(c0, p1, w1); pk_whi(c1, p1, w1);
      pk_wlo(c0, p2, w2); pk_whi(c1, p2, w2);
      pk_wlo(c0, p3, w3); pk_whi(c1, p3, w3);
    }

    // g1 = gh1 * silu'(z1); stage interleaved
    {
      float4 gg;
      gg.x = c0.x * d10A; gg.y = c0.y * d10B;
      gg.z = c1.x * d11A; gg.w = c1.y * d11B;
      *(float4*)&stgI[4 * lane] = gg;
    }

    // ---- backward through W1: grad[i] = sum_k g1[k] * W1[i][k] (LDS rows) ----
    f32x2 gr; gr.x = 0.0f; gr.y = 0.0f;        // (grA, grB)
#pragma unroll 8
    for (int k = 0; k < 128; k += 4) {
      float4 v0 = *(const float4*)&stgI[2 * k];
      float4 v1 = *(const float4*)&stgI[2 * k + 4];
      f32x2 p0; p0.x = v0.x; p0.y = v0.y;
      f32x2 p1; p1.x = v0.z; p1.y = v0.w;
      f32x2 p2; p2.x = v1.x; p2.y = v1.y;
      f32x2 p3; p3.x = v1.z; p3.y = v1.w;
      float4 w4 = *(const float4*)&W1s[lane * LDW + k];
      f32x2 w01; w01.x = w4.x; w01.y = w4.y;
      f32x2 w23; w23.x = w4.z; w23.y = w4.w;
      pk_wlo(gr, p0, w01);
      pk_whi(gr, p1, w01);
      pk_wlo(gr, p2, w23);
      pk_whi(gr, p3, w23);
    }
    grA = gr.x; grB = gr.y;
  };

  // distance from (q, qq) — identical op sequence to R14's in-loop block
  auto hypdist = [&](float xq, float yq, float qqx, float qqy) -> float {
    float df = xq - yq;
    float d2 = wsum(df * df);
    float x2 = fminf(qqx, 0.999f);
    float y2 = fminf(qqy, 0.999f);
    float arg = 1.0f + 2.0f * d2 / ((1.0f - x2) * (1.0f - y2) + EPSV);
    return acoshf(fmaxf(arg, 1.0f + EPSV));
  };

  evalgrad(qA, qB, gA, gB);  // gradV at initial positions

  // Software pipeline: qq and dist for step s are computed in iteration s-1
  // (right after the leapfrog), so the distance's wsum/acosh chain overlaps
  // evalgrad's DS-heavy opening. Values are bitwise-identical: same
  // expressions on the same input bits as the R14 ordering.
  float qq0 = wsum(qA * qA);
  float qq1 = wsum(qB * qB);
  float dist = hypdist(qA, qB, qq0, qq1);

  for (int s = 0; s < STEPS; ++s) {
    if (lane == 0) out[s * BATCH + pair] = dist;

    // leapfrog first half, trajectory A (R10 op sequence, unchanged)
    float qnA, phA;
    {
      float ph  = (pA - 0.5f * DT * gA) * (1.0f - DAMP);
      float q2r = qq0;
      float q2c = fminf(q2r, 0.999f);
      float lam = 2.0f / (1.0f - q2c);
      float v   = DT * ph / (lam * lam);
      float vn  = sqrtf(wsum(v * v)) + EPSV;
      float mag = tanhf(fminf(lam * vn * 0.5f, 15.0f));
      float y   = mag * (v / vn);
      float y2  = wsum(y * y);
      float xy  = wsum(qA * y);
      float num = (1.0f + 2.0f * xy + y2) * qA + (1.0f - q2r) * y;
      float den = 1.0f + 2.0f * xy + q2r * y2;
      float r   = num / (den + EPSV);
      float rn  = sqrtf(wsum(r * r));
      float sc  = (rn > 0.99f) ? (0.99f / (rn + EPSV)) : 1.0f;
      qnA = r * sc;
      phA = ph;
    }
    // leapfrog first half, trajectory B
    float qnB, phB;
    {
      float ph  = (pB - 0.5f * DT * gB) * (1.0f - DAMP);
      float q2r = qq1;
      float q2c = fminf(q2r, 0.999f);
      float lam = 2.0f / (1.0f - q2c);
      float v   = DT * ph / (lam * lam);
      float vn  = sqrtf(wsum(v * v)) + EPSV;
      float mag = tanhf(fminf(lam * vn * 0.5f, 15.0f));
      float y   = mag * (v / vn);
      float y2  = wsum(y * y);
      float xy  = wsum(qB * y);
      float num = (1.0f + 2.0f * xy + y2) * qB + (1.0f - q2r) * y;
      float den = 1.0f + 2.0f * xy + q2r * y2;
      float r   = num / (den + EPSV);
      float rn  = sqrtf(wsum(r * r));
      float sc  = (rn > 0.99f) ? (0.99f / (rn + EPSV)) : 1.0f;
      qnB = r * sc;
      phB = ph;
    }

    // next step's qq and distance — independent of evalgrad, overlaps it
    float nqq0 = wsum(qnA * qnA);
    float nqq1 = wsum(qnB * qnB);
    float ndist = hypdist(qnA, qnB, nqq0, nqq1);

    evalgrad(qnA, qnB, gA, gB);  // gradV(q_new); reused as next step's gradV(q)

    pA = phA - 0.5f * DT * gA; qA = qnA;
    pB = phB - 0.5f * DT * gB; qB = qnB;
    qq0 = nqq0; qq1 = nqq1; dist = ndist;
  }
}

}  // namespace

extern "C" void kernel_launch(void* const* d_in, const int* in_sizes, int n_in,
                              void* d_out, int out_size, void* d_ws, size_t ws_size,
                              hipStream_t stream) {
  (void)in_sizes; (void)n_in; (void)out_size; (void)d_ws; (void)ws_size;
  const float* q0 = (const float*)d_in[0];
  const float* pd = (const float*)d_in[1];
  const float* W1 = (const float*)d_in[2];
  const float* b1 = (const float*)d_in[3];
  const float* W2 = (const float*)d_in[4];
  const float* b2 = (const float*)d_in[5];
  const float* W3 = (const float*)d_in[6];
  // d_in[7] = b3: constant offset, does not affect gradV or distances.
  float* out = (float*)d_out;

  geo_scramble_kernel<<<dim3(512), dim3(256), 0, stream>>>(q0, pd, W1, b1, W2, b2, W3, out);
}